// Round 3
// baseline (434.547 us; speedup 1.0000x reference)
//
#include <hip/hip_runtime.h>

// PhotometricLoss: fused warp + SSIM(3x3 avgpool, zero-pad) + L1 + masked mean.
// B=8, C=3, H=720, W=1280 fp32.
//
// R6: LDS-gather redesign. R5 post-mortem: occupancy cannot be raised (85-reg
// budget -> 52MB scratch spill, dur 103->124us). R3/R4 duty analysis: VALUBusy
// 40% at ~3.5 waves/SIMD = 11% per-wave duty; ~3000 cyc exposed latency per
// row-step from the 6 data-dependent GLOBAL gathers (disp->addr->load chain,
// 200-900 cyc, re-exposed every step; R4 showed the compiler can't hide it).
// Fix: disp~N(0,1) => gather targets live in an ~80-col window per wave-strip.
// Stage that window (240 floats, wave-private LDS, double-buffered) with
// coalesced disp-INDEPENDENT prefetchable loads; gathers become ds_read2_b32
// (~60cyc, hidden). Unbounded-disp correctness via window-miss test + per-lane
// global fallback under __any (prob ~2e-5/launch, exact when taken).
// Back to known-safe __launch_bounds__(256,4) (no spills).

#define P_ALPHA 0.85f
#define P_C1 1e-4f
#define P_C2 9e-4f

constexpr int COLS  = 62;   // useful output columns per wave strip
constexpr int RPW   = 15;   // output rows per wave (720 = 12*4*15)
constexpr int WAVES = 4;    // waves per block
constexpr int PADW  = 80;   // staged right-window width per channel (cols s0-9 .. s0+70)
constexpr int NST   = 3 * PADW;  // floats per staging buffer (240)

__global__ __launch_bounds__(256, 4)
void photo_loss_kernel(const float* __restrict__ disp,
                       const float* __restrict__ left,
                       const float* __restrict__ right,
                       float* __restrict__ acc,   // acc[0]=sum(photo*valid), acc[1]=sum(valid)
                       int H, int W)
{
    __shared__ float stage[WAVES][2][NST];   // wave-private double-buffered right window
    __shared__ float redpv[WAVES];
    __shared__ float redv[WAVES];

    const int tid  = threadIdx.x;
    const int lane = tid & 63;
    const int w    = tid >> 6;
    const int b    = blockIdx.z;
    const int s0   = blockIdx.x * COLS;
    const int col  = s0 + lane - 1;                         // -1 .. W (+halo)
    const int rowStart = (blockIdx.y * WAVES + w) * RPW;
    const int W_LO = s0 - 9;                                // window start (abs col)

    const int planeHW = H * W;
    const float* __restrict__ dispb = disp  + b * planeHW;
    const float* __restrict__ L0 = left  + (b * 3 + 0) * planeHW;
    const float* __restrict__ L1 = left  + (b * 3 + 1) * planeHW;
    const float* __restrict__ L2 = left  + (b * 3 + 2) * planeHW;
    const float* __restrict__ R0 = right + (b * 3 + 0) * planeHW;
    const float* __restrict__ R1 = right + (b * 3 + 1) * planeHW;
    const float* __restrict__ R2 = right + (b * 3 + 2) * planeHW;

    const float wm1f = (float)(W - 1);
    const float colf = (float)col;
    const int   colC = min(max(col, 0), W - 1);             // clamped address col
    const float colv = (col >= 0 && col < W) ? 1.f : 0.f;   // column validity
    const float ocm  = (lane >= 1 && lane <= COLS && col < W) ? 1.f : 0.f;  // output mask

    // ---- staging roles: 240 window floats spread over 64 lanes x 4 slots ----
    int  sOff[4];    // 32-bit element offset into `right` (channel plane + srcCol)
    int  sLds[4];    // float index within a staging buffer
    bool sAct[4];
    #pragma unroll
    for (int p = 0; p < 4; ++p) {
        const int idx  = p * 64 + lane;
        sAct[p] = (idx < NST);
        const int idxc = min(idx, NST - 1);
        const int ch   = idxc / PADW;                       // 0..2 (const-div)
        const int k    = idxc - ch * PADW;                  // 0..79
        const int srcCol = min(max(W_LO + k, 0), W - 1);    // clamped source col
        sOff[p] = (b * 3 + ch) * planeHW + srcCol;
        sLds[p] = ch * PADW + k;
    }
    float* const buf0 = &stage[w][0][0];
    float* const buf1 = &stage[w][1][0];

    // 2-slot named stat ring: A = h[r-2], B = h[r-1]
    float Ax0=0.f,Ay0=0.f,Axx0=0.f,Ayy0=0.f,Axy0=0.f;
    float Ax1=0.f,Ay1=0.f,Axx1=0.f,Ayy1=0.f,Axy1=0.f;
    float Ax2=0.f,Ay2=0.f,Axx2=0.f,Ayy2=0.f,Axy2=0.f;
    float Bx0=0.f,By0=0.f,Bxx0=0.f,Byy0=0.f,Bxy0=0.f;
    float Bx1=0.f,By1=0.f,Bxx1=0.f,Byy1=0.f,Bxy1=0.f;
    float Bx2=0.f,By2=0.f,Bxx2=0.f,Byy2=0.f,Bxy2=0.f;
    float l1P=0.f, vP=0.f;

    float sum_pv = 0.f, sum_v = 0.f;

    // ---- prologue ----
    float sv0, sv1, sv2, sv3;
    const int rc0 = max(rowStart - 1, 0);
    {   // stage row rowStart-1 into buf0 (read at j=0)
        const int ro = rc0 * W;
        sv0 = right[sOff[0] + ro];
        sv1 = right[sOff[1] + ro];
        sv2 = right[sOff[2] + ro];
        sv3 = sAct[3] ? right[sOff[3] + ro] : 0.f;
        buf0[sLds[0]] = sv0; buf0[sLds[1]] = sv1; buf0[sLds[2]] = sv2;
        if (sAct[3]) buf0[sLds[3]] = sv3;
    }
    {   // prefetch staging row rowStart (written to buf1 during j=0)
        const int ro = rowStart * W;                        // rowStart in [0,H)
        sv0 = right[sOff[0] + ro];
        sv1 = right[sOff[1] + ro];
        sv2 = right[sOff[2] + ro];
        if (sAct[3]) sv3 = right[sOff[3] + ro];
    }
    float dN, xN0, xN1, xN2;
    {   // disp/left for row rowStart-1 (consumed at j=0)
        const int off = rc0 * W + colC;
        dN = dispb[off]; xN0 = L0[off]; xN1 = L1[off]; xN2 = L2[off];
    }

    #pragma unroll 2
    for (int j = 0; j < RPW + 2; ++j) {
        const int r = rowStart - 1 + j;                     // row consumed this step
        float* const bufC = (j & 1) ? buf1 : buf0;          // compile-time after unroll
        float* const bufN = (j & 1) ? buf0 : buf1;

        // take this step's in-flight disp/left (pure renames)
        const float d = dN, xc0 = xN0, xc1 = xN1, xc2 = xN2;

        // ---- issue next row's disp/left (1-step slack) ----
        if (j <= RPW) {                                     // wave-uniform
            const int rn  = min(r + 1, H - 1);              // r+1 >= rowStart >= 0
            const int off = rn * W + colC;
            dN = dispb[off]; xN0 = L0[off]; xN1 = L1[off]; xN2 = L2[off];
        }

        // ---- gather row r from wave-private LDS window ----
        const float xs  = colf - d;
        const float xcl = fminf(fmaxf(xs, 0.f), wm1f);
        const float xf  = floorf(xcl);
        const float fr  = xcl - xf;
        const int   i0  = (int)xf;
        const int   k   = i0 - W_LO;
        const int   kc  = min(max(k, 0), PADW - 2);
        float g00 = bufC[kc],            g01 = bufC[kc + 1];
        float g10 = bufC[PADW + kc],     g11 = bufC[PADW + kc + 1];
        float g20 = bufC[2 * PADW + kc], g21 = bufC[2 * PADW + kc + 1];
        const bool bad = (k < 0) || (k > PADW - 2);
        if (__builtin_expect(__any(bad), 0)) {              // ~never taken; exact fallback
            if (bad) {
                const int rc = min(max(r, 0), H - 1);
                const int ro = rc * W;
                const int i1 = min(i0 + 1, W - 1);
                g00 = R0[ro + i0]; g01 = R0[ro + i1];
                g10 = R1[ro + i0]; g11 = R1[ro + i1];
                g20 = R2[ro + i0]; g21 = R2[ro + i1];
            }
        }

        // ---- row-r horizontal stats ----
        const float rv  = (r >= 0 && r < H) ? 1.f : 0.f;
        const float m   = rv * colv;
        const float omf = 1.f - fr;
        const float y0 = (omf * g00 + fr * g01) * m;
        const float y1 = (omf * g10 + fr * g11) * m;
        const float y2 = (omf * g20 + fr * g21) * m;
        const float x0 = xc0 * m;
        const float x1 = xc1 * m;
        const float x2 = xc2 * m;

        float Cx0,Cy0,Cxx0,Cyy0,Cxy0;
        float Cx1,Cy1,Cxx1,Cyy1,Cxy1;
        float Cx2,Cy2,Cxx2,Cyy2,Cxy2;
        {
            const float xl = __shfl_up(x0,1,64), xr = __shfl_down(x0,1,64);
            const float yl = __shfl_up(y0,1,64), yr = __shfl_down(y0,1,64);
            Cx0  = xl + x0 + xr;
            Cy0  = yl + y0 + yr;
            Cxx0 = xl*xl + x0*x0 + xr*xr;
            Cyy0 = yl*yl + y0*y0 + yr*yr;
            Cxy0 = xl*yl + x0*y0 + xr*yr;
        }
        {
            const float xl = __shfl_up(x1,1,64), xr = __shfl_down(x1,1,64);
            const float yl = __shfl_up(y1,1,64), yr = __shfl_down(y1,1,64);
            Cx1  = xl + x1 + xr;
            Cy1  = yl + y1 + yr;
            Cxx1 = xl*xl + x1*x1 + xr*xr;
            Cyy1 = yl*yl + y1*y1 + yr*yr;
            Cxy1 = xl*yl + x1*y1 + xr*yr;
        }
        {
            const float xl = __shfl_up(x2,1,64), xr = __shfl_down(x2,1,64);
            const float yl = __shfl_up(y2,1,64), yr = __shfl_down(y2,1,64);
            Cx2  = xl + x2 + xr;
            Cy2  = yl + y2 + yr;
            Cxx2 = xl*xl + x2*x2 + xr*xr;
            Cyy2 = yl*yl + y2*y2 + yr*yr;
            Cxy2 = xl*yl + x2*y2 + xr*yr;
        }
        const float l1C = fabsf(x0 - y0) + fabsf(x1 - y1) + fabsf(x2 - y2);
        const float vC  = (xs > 0.f && xs < wm1f) ? 1.f : 0.f;

        // ---- emit center r-1 using (A=h[r-2], B=h[r-1], C=h[r]) ----
        if (j >= 2) {                                       // wave-uniform
            const float inv9 = 1.f / 9.f;
            float ssim_sum = 0.f;
            #define SSIM_CH(SX,SY,SXX,SYY,SXY)                                   \
            {                                                                    \
                const float mu_x = (A##SX + B##SX + C##SX) * inv9;               \
                const float mu_y = (A##SY + B##SY + C##SY) * inv9;               \
                const float exx  = (A##SXX + B##SXX + C##SXX) * inv9;            \
                const float eyy  = (A##SYY + B##SYY + C##SYY) * inv9;            \
                const float exy  = (A##SXY + B##SXY + C##SXY) * inv9;            \
                const float sig_x  = fmaxf(exx - mu_x * mu_x, 0.f);              \
                const float sig_y  = fmaxf(eyy - mu_y * mu_y, 0.f);              \
                const float sig_xy = exy - mu_x * mu_y;                          \
                const float n  = (2.f*mu_x*mu_y + P_C1) * (2.f*sig_xy + P_C2);   \
                const float dd = (mu_x*mu_x + mu_y*mu_y + P_C1)                  \
                               * (sig_x + sig_y + P_C2);                         \
                float s = (1.f - n * __builtin_amdgcn_rcpf(dd)) * 0.5f;          \
                s = fminf(fmaxf(s, 0.f), 1.f);                                   \
                ssim_sum += s;                                                   \
            }
            SSIM_CH(x0,y0,xx0,yy0,xy0)
            SSIM_CH(x1,y1,xx1,yy1,xy1)
            SSIM_CH(x2,y2,xx2,yy2,xy2)
            #undef SSIM_CH
            const float photo = P_ALPHA * (ssim_sum * (1.f / 3.f))
                              + (1.f - P_ALPHA) * (l1P * (1.f / 3.f));
            sum_pv += photo * vP * ocm;
            sum_v  += vP * ocm;
        }

        // ---- staging: write row r+1 (loaded last step), then load row r+2 ----
        if (j <= RPW) {                                     // buf for row r+1
            bufN[sLds[0]] = sv0; bufN[sLds[1]] = sv1; bufN[sLds[2]] = sv2;
            if (sAct[3]) bufN[sLds[3]] = sv3;
        }
        if (j <= RPW - 1) {                                 // load staging row r+2
            const int rs = min(r + 2, H - 1);               // r+2 >= rowStart+1 >= 1
            const int ro = rs * W;
            sv0 = right[sOff[0] + ro];
            sv1 = right[sOff[1] + ro];
            sv2 = right[sOff[2] + ro];
            if (sAct[3]) sv3 = right[sOff[3] + ro];
        }

        // ---- ring shift (renamed away inside the unroll-2 pair) ----
        Ax0=Bx0; Ay0=By0; Axx0=Bxx0; Ayy0=Byy0; Axy0=Bxy0;
        Ax1=Bx1; Ay1=By1; Axx1=Bxx1; Ayy1=Byy1; Axy1=Bxy1;
        Ax2=Bx2; Ay2=By2; Axx2=Bxx2; Ayy2=Byy2; Axy2=Bxy2;
        Bx0=Cx0; By0=Cy0; Bxx0=Cxx0; Byy0=Cyy0; Bxy0=Cxy0;
        Bx1=Cx1; By1=Cy1; Bxx1=Cxx1; Byy1=Cyy1; Bxy1=Cxy1;
        Bx2=Cx2; By2=Cy2; Bxx2=Cxx2; Byy2=Cyy2; Bxy2=Cxy2;
        l1P = l1C; vP = vC;
    }

    // wave reduce (64 lanes) then cross-wave via tiny LDS
    #pragma unroll
    for (int off = 32; off > 0; off >>= 1) {
        sum_pv += __shfl_down(sum_pv, off, 64);
        sum_v  += __shfl_down(sum_v,  off, 64);
    }
    if (lane == 0) { redpv[w] = sum_pv; redv[w] = sum_v; }
    __syncthreads();
    if (tid == 0) {
        atomicAdd(&acc[0], redpv[0] + redpv[1] + redpv[2] + redpv[3]);
        atomicAdd(&acc[1], redv[0]  + redv[1]  + redv[2]  + redv[3]);
    }
}

__global__ void photo_loss_finalize(const float* __restrict__ acc,
                                    float* __restrict__ out)
{
    out[0] = acc[0] / fmaxf(acc[1], 1.f);
}

extern "C" void kernel_launch(void* const* d_in, const int* in_sizes, int n_in,
                              void* d_out, int out_size, void* d_ws, size_t ws_size,
                              hipStream_t stream)
{
    const float* disp  = (const float*)d_in[0];
    const float* left  = (const float*)d_in[1];
    const float* right = (const float*)d_in[2];
    float* out = (float*)d_out;
    float* acc = (float*)d_ws;

    const int B = 8, H = 720, W = 1280;

    hipMemsetAsync(acc, 0, 2 * sizeof(float), stream);

    // x: 21 strips of 62 cols; y: 720 / (4 waves * 15 rows) = 12; z: batch
    dim3 grid((W + COLS - 1) / COLS, H / (WAVES * RPW), B);
    dim3 block(256);
    photo_loss_kernel<<<grid, block, 0, stream>>>(disp, left, right, acc, H, W);
    photo_loss_finalize<<<1, 1, 0, stream>>>(acc, out);
}

// Round 4
// 284.002 us; speedup vs baseline: 1.5301x; 1.5301x over previous
//
#include <hip/hip_runtime.h>

// PhotometricLoss: fused warp + SSIM(3x3 avgpool, zero-pad) + L1 + masked mean.
// B=8, C=3, H=720, W=1280 fp32.
//
// R7: shuffle-gather redesign on the R4 skeleton (the only non-spilling form:
// full unroll, 3-slot ring, 52 VGPR, 103us). R5/R6 post-mortem: rolled loops +
// staging state spill the ring to scratch (52MB/437MB WRITE_SIZE) -> always
// full-unroll. R3/R4 Little's-law: 174MB @1.7TB/s => <1 load in flight per
// wave -- the disp->addr->gather load chain serializes the memory pipeline
// and the compiler provably ignores source-level slack (R4 == R3).
// Fix: disp~N(0,1) => gather col is within ~7 of own col. Hold the whole
// 128-col window in registers: per channel two 64-wide coalesced
// disp-INDEPENDENT halo loads (rA: s0-8..s0+55, rB: s0+56..s0+119); the
// gather becomes __shfl with dynamic lane index (ds_bpermute, no memory
// latency) + select. No load->load dependence remains anywhere.
// Clamped halo addresses reproduce border-clamp gathers bit-exactly; lanes
// leaving the window (P~1e-11/pixel) take an exact per-lane global fallback
// under __any. Same load count (10/step), all coalesced, all hoistable.

#define P_ALPHA 0.85f
#define P_C1 1e-4f
#define P_C2 9e-4f

constexpr int COLS  = 62;   // useful output columns per wave strip
constexpr int RPW   = 15;   // output rows per wave (720 = 12*4*15)
constexpr int WAVES = 4;    // waves per block

__global__ __launch_bounds__(256)
void photo_loss_kernel(const float* __restrict__ disp,
                       const float* __restrict__ left,
                       const float* __restrict__ right,
                       float* __restrict__ acc,   // acc[0]=sum(photo*valid), acc[1]=sum(valid)
                       int H, int W)
{
    __shared__ float redpv[WAVES];
    __shared__ float redv[WAVES];

    const int tid  = threadIdx.x;
    const int lane = tid & 63;
    const int w    = tid >> 6;
    const int b    = blockIdx.z;
    const int s0   = blockIdx.x * COLS;
    const int col  = s0 + lane - 1;                         // -1 .. W (+halo)
    const int rowStart = (blockIdx.y * WAVES + w) * RPW;

    const int planeHW = H * W;
    const float* __restrict__ dispb = disp  + b * planeHW;
    const float* __restrict__ L0 = left  + (b * 3 + 0) * planeHW;
    const float* __restrict__ L1 = left  + (b * 3 + 1) * planeHW;
    const float* __restrict__ L2 = left  + (b * 3 + 2) * planeHW;
    const float* __restrict__ R0 = right + (b * 3 + 0) * planeHW;
    const float* __restrict__ R1 = right + (b * 3 + 1) * planeHW;
    const float* __restrict__ R2 = right + (b * 3 + 2) * planeHW;

    const float wm1f = (float)(W - 1);
    const float colf = (float)col;
    const int   colC = min(max(col, 0), W - 1);             // clamped address col
    const float colv = (col >= 0 && col < W) ? 1.f : 0.f;   // column validity
    const float ocm  = (lane >= 1 && lane <= COLS && col < W) ? 1.f : 0.f;  // output mask

    // halo columns this lane is responsible for (clamped -> border-exact)
    const int colA = min(max(s0 - 8  + lane, 0), W - 1);    // window cols s0-8 .. s0+55
    const int colB = min(max(s0 + 56 + lane, 0), W - 1);    // window cols s0+56 .. s0+119

    // 3-row register rings (all indices compile-time after full unroll)
    float rsx[3][3], rsy[3][3], rsxx[3][3], rsyy[3][3], rsxy[3][3];
    float l1r[3], vr[3];

    float sum_pv = 0.f, sum_v = 0.f;

    // emit center row held in ring slot cs (sums over all 3 slots, order-free)
    auto emit = [&](int cs) {
        const float inv9 = 1.f / 9.f;
        float ssim_sum = 0.f;
        #pragma unroll
        for (int c = 0; c < 3; ++c) {
            float mu_x = (rsx[c][0]  + rsx[c][1]  + rsx[c][2])  * inv9;
            float mu_y = (rsy[c][0]  + rsy[c][1]  + rsy[c][2])  * inv9;
            float exx  = (rsxx[c][0] + rsxx[c][1] + rsxx[c][2]) * inv9;
            float eyy  = (rsyy[c][0] + rsyy[c][1] + rsyy[c][2]) * inv9;
            float exy  = (rsxy[c][0] + rsxy[c][1] + rsxy[c][2]) * inv9;
            float sig_x  = fmaxf(exx - mu_x * mu_x, 0.f);
            float sig_y  = fmaxf(eyy - mu_y * mu_y, 0.f);
            float sig_xy = exy - mu_x * mu_y;
            float n  = (2.f * mu_x * mu_y + P_C1) * (2.f * sig_xy + P_C2);
            float dd = (mu_x * mu_x + mu_y * mu_y + P_C1) * (sig_x + sig_y + P_C2);
            float s  = (1.f - n * __builtin_amdgcn_rcpf(dd)) * 0.5f;  // dd >= C1*C2 > 0
            s = fminf(fmaxf(s, 0.f), 1.f);
            ssim_sum += s;
        }
        float photo = P_ALPHA * (ssim_sum * (1.f / 3.f))
                    + (1.f - P_ALPHA) * (l1r[cs] * (1.f / 3.f));
        sum_pv += photo * vr[cs] * ocm;
        sum_v  += vr[cs] * ocm;
    };

    // pipeline registers: all loads for the row processed THIS step
    // (disp, left x3, right-halo x6 -- every one coalesced & disp-independent)
    float dC, xC0, xC1, xC2;
    float hA0, hA1, hA2, hB0, hB1, hB2;
    {
        const int rc  = max(rowStart - 1, 0);
        const int off = rc * W + colC;
        dC = dispb[off]; xC0 = L0[off]; xC1 = L1[off]; xC2 = L2[off];
        const int ro = rc * W;
        hA0 = R0[ro + colA]; hB0 = R0[ro + colB];
        hA1 = R1[ro + colA]; hB1 = R1[ro + colB];
        hA2 = R2[ro + colA]; hB2 = R2[ro + colB];
    }

    #pragma unroll
    for (int j = 0; j <= RPW + 2; ++j) {
        const int s = j % 3;                    // ring slot to write (compile-time)
        const int r = rowStart - 1 + j;         // row processed this step
        if (j <= RPW + 1) {
            // ---- prefetch row r+1 (all independent, coalesced) ----
            float dN = 0.f, xN0 = 0.f, xN1 = 0.f, xN2 = 0.f;
            float nA0 = 0.f, nA1 = 0.f, nA2 = 0.f, nB0 = 0.f, nB1 = 0.f, nB2 = 0.f;
            if (j <= RPW) {
                const int rn   = min(r + 1, H - 1);          // r+1 >= rowStart >= 0
                const int offn = rn * W + colC;
                dN = dispb[offn]; xN0 = L0[offn]; xN1 = L1[offn]; xN2 = L2[offn];
                const int ron = rn * W;
                nA0 = R0[ron + colA]; nB0 = R0[ron + colB];
                nA1 = R1[ron + colA]; nB1 = R1[ron + colB];
                nA2 = R2[ron + colA]; nB2 = R2[ron + colB];
            }

            // ---- gather row r from halo REGISTERS via dynamic shuffle ----
            const float xs  = colf - dC;
            const float xcl = fminf(fmaxf(xs, 0.f), wm1f);
            const float xf  = floorf(xcl);
            const float fr  = xcl - xf;
            const int   i0  = (int)xf;
            const int   k   = i0 - s0 + 8;       // index into 128-col window
            const int   k1  = k + 1;
            const int   ks  = k & 63;
            const int   k1s = k1 & 63;
            float g00, g01, g10, g11, g20, g21;
            {
                const float a  = __shfl(hA0, ks, 64),  bb = __shfl(hB0, ks, 64);
                const float a1 = __shfl(hA0, k1s, 64), b1 = __shfl(hB0, k1s, 64);
                g00 = (k  < 64) ? a  : bb;
                g01 = (k1 < 64) ? a1 : b1;
            }
            {
                const float a  = __shfl(hA1, ks, 64),  bb = __shfl(hB1, ks, 64);
                const float a1 = __shfl(hA1, k1s, 64), b1 = __shfl(hB1, k1s, 64);
                g10 = (k  < 64) ? a  : bb;
                g11 = (k1 < 64) ? a1 : b1;
            }
            {
                const float a  = __shfl(hA2, ks, 64),  bb = __shfl(hB2, ks, 64);
                const float a1 = __shfl(hA2, k1s, 64), b1 = __shfl(hB2, k1s, 64);
                g20 = (k  < 64) ? a  : bb;
                g21 = (k1 < 64) ? a1 : b1;
            }
            // window miss (|disp| > ~70): exact per-lane global fallback, ~never taken
            const bool bad = (k < 0) || (k1 > 127);
            if (__builtin_expect(__any(bad), 0)) {
                if (bad) {
                    const int rc = min(max(r, 0), H - 1);
                    const int ro = rc * W;
                    const int i1 = min(i0 + 1, W - 1);
                    g00 = R0[ro + i0]; g01 = R0[ro + i1];
                    g10 = R1[ro + i0]; g11 = R1[ro + i1];
                    g20 = R2[ro + i0]; g21 = R2[ro + i1];
                }
            }

            // ---- emit center r-2 (pure VALU) ----
            if (j >= 3) emit((s + 1) % 3);

            // ---- row-r values + horizontal stats into ring slot s ----
            const float rv  = (r >= 0 && r < H) ? 1.f : 0.f;
            const float m   = rv * colv;
            const float omf = 1.f - fr;
            const float y0 = (omf * g00 + fr * g01) * m;
            const float y1 = (omf * g10 + fr * g11) * m;
            const float y2 = (omf * g20 + fr * g21) * m;
            const float x0 = xC0 * m;
            const float x1 = xC1 * m;
            const float x2 = xC2 * m;

            float xl, xr, yl, yr;
            xl = __shfl_up(x0, 1, 64); xr = __shfl_down(x0, 1, 64);
            yl = __shfl_up(y0, 1, 64); yr = __shfl_down(y0, 1, 64);
            rsx[0][s]  = xl + x0 + xr;
            rsy[0][s]  = yl + y0 + yr;
            rsxx[0][s] = xl * xl + x0 * x0 + xr * xr;
            rsyy[0][s] = yl * yl + y0 * y0 + yr * yr;
            rsxy[0][s] = xl * yl + x0 * y0 + xr * yr;

            xl = __shfl_up(x1, 1, 64); xr = __shfl_down(x1, 1, 64);
            yl = __shfl_up(y1, 1, 64); yr = __shfl_down(y1, 1, 64);
            rsx[1][s]  = xl + x1 + xr;
            rsy[1][s]  = yl + y1 + yr;
            rsxx[1][s] = xl * xl + x1 * x1 + xr * xr;
            rsyy[1][s] = yl * yl + y1 * y1 + yr * yr;
            rsxy[1][s] = xl * yl + x1 * y1 + xr * yr;

            xl = __shfl_up(x2, 1, 64); xr = __shfl_down(x2, 1, 64);
            yl = __shfl_up(y2, 1, 64); yr = __shfl_down(y2, 1, 64);
            rsx[2][s]  = xl + x2 + xr;
            rsy[2][s]  = yl + y2 + yr;
            rsxx[2][s] = xl * xl + x2 * x2 + xr * xr;
            rsyy[2][s] = yl * yl + y2 * y2 + yr * yr;
            rsxy[2][s] = xl * yl + x2 * y2 + xr * yr;

            l1r[s] = fabsf(x0 - y0) + fabsf(x1 - y1) + fabsf(x2 - y2);
            vr[s]  = (xs > 0.f && xs < wm1f) ? 1.f : 0.f;

            // rotate pipeline
            dC = dN; xC0 = xN0; xC1 = xN1; xC2 = xN2;
            hA0 = nA0; hA1 = nA1; hA2 = nA2;
            hB0 = nB0; hB1 = nB1; hB2 = nB2;
        } else {
            emit((s + 1) % 3);                  // final center rowStart+RPW-1
        }
    }

    // wave reduce (64 lanes) then cross-wave via tiny LDS
    #pragma unroll
    for (int off = 32; off > 0; off >>= 1) {
        sum_pv += __shfl_down(sum_pv, off, 64);
        sum_v  += __shfl_down(sum_v,  off, 64);
    }
    if (lane == 0) { redpv[w] = sum_pv; redv[w] = sum_v; }
    __syncthreads();
    if (tid == 0) {
        atomicAdd(&acc[0], redpv[0] + redpv[1] + redpv[2] + redpv[3]);
        atomicAdd(&acc[1], redv[0]  + redv[1]  + redv[2]  + redv[3]);
    }
}

__global__ void photo_loss_finalize(const float* __restrict__ acc,
                                    float* __restrict__ out)
{
    out[0] = acc[0] / fmaxf(acc[1], 1.f);
}

extern "C" void kernel_launch(void* const* d_in, const int* in_sizes, int n_in,
                              void* d_out, int out_size, void* d_ws, size_t ws_size,
                              hipStream_t stream)
{
    const float* disp  = (const float*)d_in[0];
    const float* left  = (const float*)d_in[1];
    const float* right = (const float*)d_in[2];
    float* out = (float*)d_out;
    float* acc = (float*)d_ws;

    const int B = 8, H = 720, W = 1280;

    hipMemsetAsync(acc, 0, 2 * sizeof(float), stream);

    // x: 21 strips of 62 cols; y: 720 / (4 waves * 15 rows) = 12; z: batch
    dim3 grid((W + COLS - 1) / COLS, H / (WAVES * RPW), B);
    dim3 block(256);
    photo_loss_kernel<<<grid, block, 0, stream>>>(disp, left, right, acc, H, W);
    photo_loss_finalize<<<1, 1, 0, stream>>>(acc, out);
}